// Round 2
// baseline (291.131 us; speedup 1.0000x reference)
//
#include <hip/hip_runtime.h>
#include <stdint.h>

typedef unsigned short u16;
typedef _Float16 f16;
typedef __attribute__((ext_vector_type(8))) _Float16 f16x8;
typedef __attribute__((ext_vector_type(4))) float f32x4;
typedef __attribute__((ext_vector_type(4))) int i32x4;

// LDS row stride: 56 f16 = 112 B (16B-aligned for ds_read_b128, 28 dwords -> max
// 2-way bank aliasing on frag reads/writes; 2-way is free per m136).
#define LW 56
#define LWI 28

// Barrier that drains LDS (lgkmcnt) but NOT vmcnt: register prefetch loads stay
// in flight across it (hipBLASLt/AITER pattern; __syncthreads would vmcnt(0)-drain).
#define BARRIER() asm volatile("s_waitcnt lgkmcnt(0)\n\ts_barrier" ::: "memory")

__device__ __forceinline__ int pk2(float a, float b) {
  return __builtin_bit_cast(int, __builtin_amdgcn_cvt_pkrtz(a, b));
}

// ---------------- prep kernels ----------------

// x fp32 -> fp16 (pkrtz), 8 elems/thread
__global__ __launch_bounds__(256) void cvt_x(const float* __restrict__ src,
                                             i32x4* __restrict__ dst, int n8) {
  int t = blockIdx.x * 256 + threadIdx.x;
  if (t >= n8) return;
  f32x4 a = ((const f32x4*)src)[2 * t];
  f32x4 b = ((const f32x4*)src)[2 * t + 1];
  i32x4 o = {pk2(a[0], a[1]), pk2(a[2], a[3]), pk2(b[0], b[1]), pk2(b[2], b[3])};
  dst[t] = o;
}

__global__ __launch_bounds__(256) void bias_init(float* __restrict__ out,
                                                 const float* __restrict__ b, int n4) {
  int t = blockIdx.x * 256 + threadIdx.x;
  if (t >= n4) return;
  int idx = t * 4;
  *(f32x4*)(out + idx) = *(const f32x4*)(b + (idx & 2047));
}

// ---------------- GEMM1: h = relu(x @ w1^T + b1), fused int4 dequant ----------------
// M=512, N=8192, K=2048. Tile 64(M)x128(N), BK=32, 256 thr, grid (64,8)=512 blocks (2/CU).
// Wave w: rows wm=(w>>1)*32 (2 m-16-tiles), cols wn=(w&1)*64 (4 n-16-tiles).
__global__ __launch_bounds__(256, 2) void gemm1(const u16* __restrict__ X,
                                                const int* __restrict__ Q,
                                                const float* __restrict__ S,
                                                const float* __restrict__ Z,
                                                const float* __restrict__ bias,
                                                f16* __restrict__ H) {
  const int K = 2048, N = 8192, G = 16;
  __shared__ int As[2][64 * LWI];
  __shared__ int Bs[2][128 * LWI];
  const int tid = threadIdx.x;
  const int wave = tid >> 6, lane = tid & 63, quad = lane >> 4, l15 = lane & 15;
  const int m0 = blockIdx.y << 6, n0 = blockIdx.x << 7;
  const int wm = (wave >> 1) << 5, wn = (wave & 1) << 6;
  const int arow = tid >> 2, ak = (tid & 3) << 3;  // A: 8 f16 per thread
  const int brow = tid >> 1, bk = (tid & 1) << 4;  // B: 16 int32 per thread

  const u16* ap = X + (size_t)(m0 + arow) * K + ak;
  const int* qp = Q + (size_t)(n0 + brow) * K + bk;
  const float* sp = S + (n0 + brow) * G;
  const float* zp = Z + (n0 + brow) * G;

  // prefetch k=0
  i32x4 nq0 = *(const i32x4*)(qp);
  i32x4 nq1 = *(const i32x4*)(qp + 4);
  i32x4 nq2 = *(const i32x4*)(qp + 8);
  i32x4 nq3 = *(const i32x4*)(qp + 12);
  i32x4 na = *(const i32x4*)(ap);
  float ns = sp[0], nz = zp[0];

  f32x4 acc[2][4];
#pragma unroll
  for (int i = 0; i < 2; i++)
#pragma unroll
    for (int j = 0; j < 4; j++) acc[i][j] = (f32x4){0.f, 0.f, 0.f, 0.f};

#pragma unroll 2
  for (int k = 0; k < K; k += 32) {
    const int buf = (k >> 5) & 1;
    i32x4 q0 = nq0, q1 = nq1, q2 = nq2, q3 = nq3, av = na;
    const float f = ns, o = -nz * ns;
    if (k + 32 < K) {  // uniform branch; next-iter prefetch (stays in flight across barrier)
      nq0 = *(const i32x4*)(qp + k + 32);
      nq1 = *(const i32x4*)(qp + k + 36);
      nq2 = *(const i32x4*)(qp + k + 40);
      nq3 = *(const i32x4*)(qp + k + 44);
      na = *(const i32x4*)(ap + k + 32);
      const int g = (k + 32) >> 7;
      ns = sp[g];
      nz = zp[g];
    }
    // dequant 16 ints -> 16 fp16 (w = q*s - z*s), pack pairs via v_cvt_pkrtz
    i32x4 lo = {pk2(fmaf((float)q0[0], f, o), fmaf((float)q0[1], f, o)),
                pk2(fmaf((float)q0[2], f, o), fmaf((float)q0[3], f, o)),
                pk2(fmaf((float)q1[0], f, o), fmaf((float)q1[1], f, o)),
                pk2(fmaf((float)q1[2], f, o), fmaf((float)q1[3], f, o))};
    i32x4 hi = {pk2(fmaf((float)q2[0], f, o), fmaf((float)q2[1], f, o)),
                pk2(fmaf((float)q2[2], f, o), fmaf((float)q2[3], f, o)),
                pk2(fmaf((float)q3[0], f, o), fmaf((float)q3[1], f, o)),
                pk2(fmaf((float)q3[2], f, o), fmaf((float)q3[3], f, o))};
    *(i32x4*)&Bs[buf][brow * LWI + (bk >> 1)] = lo;
    *(i32x4*)&Bs[buf][brow * LWI + (bk >> 1) + 4] = hi;
    *(i32x4*)&As[buf][arow * LWI + (ak >> 1)] = av;
    BARRIER();  // one barrier/iter: LDS double-buffered, reads of buf^1 done pre-barrier
    const f16* AsH = (const f16*)As[buf];
    const f16* BsH = (const f16*)Bs[buf];
    f16x8 af[2], bf[4];
#pragma unroll
    for (int i = 0; i < 2; i++)
      af[i] = *(const f16x8*)&AsH[(wm + i * 16 + l15) * LW + quad * 8];
#pragma unroll
    for (int j = 0; j < 4; j++)
      bf[j] = *(const f16x8*)&BsH[(wn + j * 16 + l15) * LW + quad * 8];
#pragma unroll
    for (int i = 0; i < 2; i++)
#pragma unroll
      for (int j = 0; j < 4; j++)
        acc[i][j] = __builtin_amdgcn_mfma_f32_16x16x32_f16(af[i], bf[j], acc[i][j], 0, 0, 0);
  }

  // epilogue: C/D layout col=lane&15, row=quad*4+reg; bias+relu, fp16 store
#pragma unroll
  for (int i = 0; i < 2; i++)
#pragma unroll
    for (int j = 0; j < 4; j++) {
      const int col = n0 + wn + j * 16 + l15;
      const float bv = bias[col];
#pragma unroll
      for (int r = 0; r < 4; r++) {
        const int row = m0 + wm + i * 16 + quad * 4 + r;
        float v = acc[i][j][r] + bv;
        v = v > 0.f ? v : 0.f;
        H[(size_t)row * N + col] = (f16)v;
      }
    }
}

// ---------------- GEMM2: out += h @ w2^T (split-K=8, atomic), fused int4 dequant ----
// M=512, N=2048, K=8192. Tile 128x128, BK=32, kChunk=1024, grid (16,4,8)=512 blocks.
__global__ __launch_bounds__(256, 2) void gemm2(const u16* __restrict__ Hm,
                                                const int* __restrict__ Q,
                                                const float* __restrict__ S,
                                                const float* __restrict__ Z,
                                                float* __restrict__ out) {
  const int K = 8192, N = 2048, G = 64, KCH = 1024;
  __shared__ int As[2][128 * LWI];
  __shared__ int Bs[2][128 * LWI];
  const int tid = threadIdx.x;
  const int wave = tid >> 6, lane = tid & 63, quad = lane >> 4, l15 = lane & 15;
  const int m0 = blockIdx.y << 7, n0 = blockIdx.x << 7;
  const int kStart = blockIdx.z << 10;
  const int wm = (wave >> 1) << 6, wn = (wave & 1) << 6;
  const int arow = tid >> 1, ak = (tid & 1) << 4;  // A: 16 f16 per thread
  const int brow = tid >> 1, bk = (tid & 1) << 4;  // B: 16 int32 per thread

  const u16* ap = Hm + (size_t)(m0 + arow) * K + kStart + ak;
  const int* qp = Q + (size_t)(n0 + brow) * K + kStart + bk;
  const float* sp = S + (n0 + brow) * G;
  const float* zp = Z + (n0 + brow) * G;
  const int g0 = kStart >> 7;

  i32x4 nq0 = *(const i32x4*)(qp);
  i32x4 nq1 = *(const i32x4*)(qp + 4);
  i32x4 nq2 = *(const i32x4*)(qp + 8);
  i32x4 nq3 = *(const i32x4*)(qp + 12);
  i32x4 na0 = *(const i32x4*)(ap);
  i32x4 na1 = *(const i32x4*)(ap + 8);
  float ns = sp[g0], nz = zp[g0];

  f32x4 acc[4][4];
#pragma unroll
  for (int i = 0; i < 4; i++)
#pragma unroll
    for (int j = 0; j < 4; j++) acc[i][j] = (f32x4){0.f, 0.f, 0.f, 0.f};

#pragma unroll 2
  for (int k = 0; k < KCH; k += 32) {
    const int buf = (k >> 5) & 1;
    i32x4 q0 = nq0, q1 = nq1, q2 = nq2, q3 = nq3, a0 = na0, a1 = na1;
    const float f = ns, o = -nz * ns;
    if (k + 32 < KCH) {
      nq0 = *(const i32x4*)(qp + k + 32);
      nq1 = *(const i32x4*)(qp + k + 36);
      nq2 = *(const i32x4*)(qp + k + 40);
      nq3 = *(const i32x4*)(qp + k + 44);
      na0 = *(const i32x4*)(ap + k + 32);
      na1 = *(const i32x4*)(ap + k + 40);
      const int g = (kStart + k + 32) >> 7;
      ns = sp[g];
      nz = zp[g];
    }
    i32x4 lo = {pk2(fmaf((float)q0[0], f, o), fmaf((float)q0[1], f, o)),
                pk2(fmaf((float)q0[2], f, o), fmaf((float)q0[3], f, o)),
                pk2(fmaf((float)q1[0], f, o), fmaf((float)q1[1], f, o)),
                pk2(fmaf((float)q1[2], f, o), fmaf((float)q1[3], f, o))};
    i32x4 hi = {pk2(fmaf((float)q2[0], f, o), fmaf((float)q2[1], f, o)),
                pk2(fmaf((float)q2[2], f, o), fmaf((float)q2[3], f, o)),
                pk2(fmaf((float)q3[0], f, o), fmaf((float)q3[1], f, o)),
                pk2(fmaf((float)q3[2], f, o), fmaf((float)q3[3], f, o))};
    *(i32x4*)&Bs[buf][brow * LWI + (bk >> 1)] = lo;
    *(i32x4*)&Bs[buf][brow * LWI + (bk >> 1) + 4] = hi;
    *(i32x4*)&As[buf][arow * LWI + (ak >> 1)] = a0;
    *(i32x4*)&As[buf][arow * LWI + (ak >> 1) + 4] = a1;
    BARRIER();
    const f16* AsH = (const f16*)As[buf];
    const f16* BsH = (const f16*)Bs[buf];
    f16x8 af[4], bf[4];
#pragma unroll
    for (int i = 0; i < 4; i++)
      af[i] = *(const f16x8*)&AsH[(wm + i * 16 + l15) * LW + quad * 8];
#pragma unroll
    for (int j = 0; j < 4; j++)
      bf[j] = *(const f16x8*)&BsH[(wn + j * 16 + l15) * LW + quad * 8];
#pragma unroll
    for (int i = 0; i < 4; i++)
#pragma unroll
      for (int j = 0; j < 4; j++)
        acc[i][j] = __builtin_amdgcn_mfma_f32_16x16x32_f16(af[i], bf[j], acc[i][j], 0, 0, 0);
  }

#pragma unroll
  for (int i = 0; i < 4; i++)
#pragma unroll
    for (int j = 0; j < 4; j++) {
      const int col = n0 + wn + j * 16 + l15;
#pragma unroll
      for (int r = 0; r < 4; r++) {
        const int row = m0 + wm + i * 16 + quad * 4 + r;
        atomicAdd(out + (size_t)row * N + col, acc[i][j][r]);
      }
    }
}

// ---------------- launch ----------------

extern "C" void kernel_launch(void* const* d_in, const int* in_sizes, int n_in,
                              void* d_out, int out_size, void* d_ws, size_t ws_size,
                              hipStream_t stream) {
  const float* x = (const float*)d_in[0];
  const int* q1 = (const int*)d_in[1];
  const float* s1 = (const float*)d_in[2];
  const float* z1 = (const float*)d_in[3];
  const float* b1 = (const float*)d_in[4];
  const int* q2 = (const int*)d_in[5];
  const float* s2 = (const float*)d_in[6];
  const float* z2 = (const float*)d_in[7];
  const float* b2 = (const float*)d_in[8];
  float* out = (float*)d_out;

  const int B = 512, D_IN = 2048, D_H = 8192, D_OUT = 2048;

  char* ws = (char*)d_ws;
  u16* xh = (u16*)ws;                                  // 2 MB: x fp16 [512][2048]
  u16* h = (u16*)(ws + (size_t)2 * 1024 * 1024);       // 8 MB: h fp16 [512][8192]

  cvt_x<<<(B * D_IN / 8 + 255) / 256, 256, 0, stream>>>(x, (i32x4*)xh, B * D_IN / 8);
  bias_init<<<(B * D_OUT / 4 + 255) / 256, 256, 0, stream>>>(out, b2, B * D_OUT / 4);

  dim3 g1(D_H / 128, B / 64, 1);  // (64, 8) = 512 blocks
  gemm1<<<g1, 256, 0, stream>>>(xh, q1, s1, z1, b1, (f16*)h);

  dim3 g2(D_OUT / 128, B / 128, 8);  // (16, 4, 8) = 512 blocks
  gemm2<<<g2, 256, 0, stream>>>(h, q2, s2, z2, out);
}